// Round 4
// baseline (357.970 us; speedup 1.0000x reference)
//
#include <hip/hip_runtime.h>
#include <hip/hip_cooperative_groups.h>
#include <cstdint>

namespace cg = cooperative_groups;

#define TPB 256
#define IT 8        // i-rows per thread -> 2048 rows per block
#define JCHUNK 256  // j-columns staged in LDS per block (4 KiB)

// gt = R*kp + t and |gt|^2, bit-matching the numpy reference (validated
// absmax=0.0 in R1-R3): ascending-k FMA chain; sum of squares as (a+b)+c
// with contraction off.
__device__ __forceinline__ float4 compute_gt(const float* __restrict__ kp,
                                             const float* __restrict__ P) {
    float k0 = kp[0], k1 = kp[1], k2 = kp[2];
    float g0 = fmaf(P[2],  k2, fmaf(P[1], k1, P[0]*k0)) + P[3];
    float g1 = fmaf(P[6],  k2, fmaf(P[5], k1, P[4]*k0)) + P[7];
    float g2 = fmaf(P[10], k2, fmaf(P[9], k1, P[8]*k0)) + P[11];
    float sg;
    {
        #pragma clang fp contract(off)
        sg = (g0*g0 + g1*g1) + g2*g2;
    }
    return make_float4(g0, g1, g2, sg);
}

__device__ __forceinline__ float wave_red(float v) {
    #pragma unroll
    for (int off = 32; off > 0; off >>= 1) v += __shfl_down(v, off, 64);
    return v;
}

// One cooperative kernel, 4 phases separated by grid.sync():
//  P0: zero good[] + accum (replaces memset node)
//  P1: per-(row-tile, j-chunk) "good" flags; j-loop is a pure fmin reduction
//      with NOTHING extra live (thr recomputed after the loop -> no spills);
//      exact first-occurrence ties via <=/< split + equality-triggered scan.
//  P2: finalize reduction (balanced BCE from good[i]==numJ, weighted L1)
//  P3: scalar combine -> out[0]
__global__ void __launch_bounds__(TPB, 2) fused_kernel(
        const float* __restrict__ kp,
        const float* __restrict__ pred,
        const float* __restrict__ pose,
        const float* __restrict__ ow,
        const float* __restrict__ logits,
        unsigned int* __restrict__ good,
        float* __restrict__ accum,
        float* __restrict__ out,
        int M, int N, int numI, int numJ) {
    cg::grid_group grid = cg::this_grid();
    __shared__ float4 sh[JCHUNK];
    __shared__ float red[4 * 6];

    int gtid = blockIdx.x * TPB + threadIdx.x;
    int gstride = gridDim.x * TPB;

    // ---------------- Phase 0: zero workspace ----------------
    for (int i = gtid; i < M; i += gstride) good[i] = 0u;
    if (gtid < 8) accum[gtid] = 0.0f;
    grid.sync();

    // ---------------- Phase 1: flags ----------------
    int ic = blockIdx.x % numI;
    int jc = blockIdx.x / numI;
    int j0 = jc * JCHUNK;
    int jmax = M - j0; if (jmax > JCHUNK) jmax = JCHUNK;

    // stage this chunk's gt into LDS (computed from kp+pose, not loaded)
    for (int k = threadIdx.x; k < jmax; k += TPB) {
        int j = j0 + k;
        sh[k] = compute_gt(kp + 3*j, pose + (j / N) * 12);
    }
    __syncthreads();

    // per-row read-only state + running min: 5*IT = 40 VGPRs, nothing else
    float tp0[IT], tp1[IT], tp2[IT], sp[IT], m[IT];
    int ibase = ic * (TPB * IT) + threadIdx.x;
    #pragma unroll
    for (int k = 0; k < IT; k++) {
        int i = ibase + k * TPB;
        if (i >= M) i = M - 1;
        float p0 = pred[3*i+0], p1 = pred[3*i+1], p2 = pred[3*i+2];
        {
            #pragma clang fp contract(off)
            sp[k] = (p0*p0 + p1*p1) + p2*p2;
        }
        tp0[k] = 2.0f * p0;   // 2*dot via exact operand prescale
        tp1[k] = 2.0f * p1;
        tp2[k] = 2.0f * p2;
        m[k] = __uint_as_float(0x7f7fffffu);  // FLT_MAX
    }

    int j = 0;
    for (; j + 1 < jmax; j += 2) {
        float4 ga = sh[j];
        float4 gb = sh[j + 1];
        #pragma unroll
        for (int k = 0; k < IT; k++) {
            float va = (sp[k] + ga.w) -
                       fmaf(tp2[k], ga.z, fmaf(tp1[k], ga.y, tp0[k] * ga.x));
            float vb = (sp[k] + gb.w) -
                       fmaf(tp2[k], gb.z, fmaf(tp1[k], gb.y, tp0[k] * gb.x));
            m[k] = fminf(fminf(va, vb), m[k]);   // -> v_min3_f32
        }
    }
    if (j < jmax) {
        float4 ga = sh[j];
        #pragma unroll
        for (int k = 0; k < IT; k++) {
            float va = (sp[k] + ga.w) -
                       fmaf(tp2[k], ga.z, fmaf(tp1[k], ga.y, tp0[k] * ga.x));
            m[k] = fminf(va, m[k]);
        }
    }

    // post-loop: recompute thr (diag distance) per row; exact tie handling.
    int j1 = j0 + jmax;
    #pragma unroll
    for (int k = 0; k < IT; k++) {
        int i = ibase + k * TPB;
        if (i >= M) continue;
        float4 gi = compute_gt(kp + 3*i, pose + (i / N) * 12);
        float dot2 = fmaf(tp2[k], gi.z, fmaf(tp1[k], gi.y, tp0[k] * gi.x));
        float dii = fmaxf((sp[k] + gi.w) - dot2, 0.0f);
        float vminc = fmaxf(m[k], 0.0f);   // clamp commutes with min
        bool bad;
        if (i >= j1) {
            bad = (vminc <= dii);          // whole chunk is j < i
        } else {
            bad = (vminc < dii);           // strict covers j >= i (diag safe)
            // equality can only matter for the prefix j in [j0, min(i,j1));
            // vminc==dii arises (for real data) only via the diagonal.
            if (!bad && vminc == dii && i > j0) {
                int je = (i < j1 ? i : j1) - j0;
                for (int jj = 0; jj < je; jj++) {
                    float4 g = sh[jj];
                    float v = (sp[k] + g.w) -
                              fmaf(tp2[k], g.z, fmaf(tp1[k], g.y, tp0[k] * g.x));
                    if (fmaxf(v, 0.0f) <= dii) { bad = true; break; }
                }
            }
        }
        if (!bad) atomicAdd(&good[i], 1u);   // ~1/(JCHUNK+1) of (row,chunk)
    }
    grid.sync();

    // ---------------- Phase 2: finalize reduction ----------------
    float werr = 0.f, wsum = 0.f, b1 = 0.f, c1 = 0.f, b0 = 0.f, c0 = 0.f;
    for (int i = gtid; i < M; i += gstride) {
        unsigned int g = __hip_atomic_load(&good[i], __ATOMIC_RELAXED,
                                           __HIP_MEMORY_SCOPE_AGENT);
        float x = logits[i];
        float l1p = log1pf(expf(-fabsf(x)));   // softplus tail
        if (g == (unsigned int)numJ) {         // label 1: softplus(-x)
            b1 += fmaxf(-x, 0.f) + l1p; c1 += 1.f;
        } else {                               // label 0: softplus(x)
            b0 += fmaxf(x, 0.f) + l1p;  c0 += 1.f;
        }
        float4 gg = compute_gt(kp + 3*i, pose + (i / N) * 12);
        float p0 = pred[3*i+0], p1 = pred[3*i+1], p2 = pred[3*i+2];
        float e = (fabsf(p0 - gg.x) + fabsf(p1 - gg.y)) + fabsf(p2 - gg.z);
        float wi = ow[i];
        werr += wi * e;
        wsum += wi;
    }
    werr = wave_red(werr); wsum = wave_red(wsum);
    b1 = wave_red(b1); c1 = wave_red(c1);
    b0 = wave_red(b0); c0 = wave_red(c0);
    if ((threadIdx.x & 63) == 0) {
        int has = (werr != 0.f) + 1;  // cheap guard against compiler sinking
        (void)has;
        atomicAdd(&accum[0], werr);
        atomicAdd(&accum[1], wsum);
        atomicAdd(&accum[2], b1);
        atomicAdd(&accum[3], c1);
        atomicAdd(&accum[4], b0);
        atomicAdd(&accum[5], c0);
    }
    grid.sync();

    // ---------------- Phase 3: scalar combine ----------------
    if (gtid == 0) {
        float t[6];
        #pragma unroll
        for (int q = 0; q < 6; q++)
            t[q] = __hip_atomic_load(&accum[q], __ATOMIC_RELAXED,
                                     __HIP_MEMORY_SCOPE_AGENT);
        float mean_err = t[0] / fmaxf(t[1], 1e-6f);
        float g1v = (t[3] > 0.f) ? (t[2] / fmaxf(t[3], 1.f)) : 0.f;
        float g0v = (t[5] > 0.f) ? (t[4] / fmaxf(t[5], 1.f)) : 0.f;
        out[0] = mean_err + (g0v * 0.5f + g1v * 0.5f);
    }
}

extern "C" void kernel_launch(void* const* d_in, const int* in_sizes, int n_in,
                              void* d_out, int out_size, void* d_ws, size_t ws_size,
                              hipStream_t stream) {
    const float* kp     = (const float*)d_in[0];
    const float* pred   = (const float*)d_in[1];
    const float* pose   = (const float*)d_in[2];
    const float* ow     = (const float*)d_in[3];
    const float* logits = (const float*)d_in[4];
    float* out = (float*)d_out;

    int M = in_sizes[3];            // B*N = 16384
    int B = in_sizes[2] / 12;       // 2
    int N = M / B;                  // 8192

    unsigned int* good = (unsigned int*)d_ws;                    // M u32
    float* accum = (float*)((char*)d_ws + (size_t)M * 4);        // 32 B

    int numI = (M + TPB * IT - 1) / (TPB * IT);                  // 8
    int numJ = (M + JCHUNK - 1) / JCHUNK;                        // 64
    int nblocks = numI * numJ;                                   // 512 (2/CU)

    void* args[] = { (void*)&kp, (void*)&pred, (void*)&pose, (void*)&ow,
                     (void*)&logits, (void*)&good, (void*)&accum, (void*)&out,
                     (void*)&M, (void*)&N, (void*)&numI, (void*)&numJ };
    hipLaunchCooperativeKernel((void*)fused_kernel, dim3(nblocks), dim3(TPB),
                               args, 0, stream);
}

// Round 5
// 167.913 us; speedup vs baseline: 2.1319x; 2.1319x over previous
//
#include <hip/hip_runtime.h>
#include <cstdint>

#define TPB 256
#define IT 8        // i-rows per thread -> 2048 rows per block
#define JCHUNK 128  // j-columns staged in LDS per block (2 KiB)

// gt = R*kp + t and |gt|^2, bit-matching the numpy reference (validated
// absmax=0.0 R1-R4): ascending-k FMA chain; +t plain add; sum of squares
// as (a*a + b*b) + c*c with explicit non-contracted intrinsics.
__device__ __forceinline__ float4 compute_gt(const float* __restrict__ kp,
                                             const float* __restrict__ P) {
    float k0 = kp[0], k1 = kp[1], k2 = kp[2];
    float g0 = fmaf(P[2],  k2, fmaf(P[1], k1, P[0]*k0)) + P[3];
    float g1 = fmaf(P[6],  k2, fmaf(P[5], k1, P[4]*k0)) + P[7];
    float g2 = fmaf(P[10], k2, fmaf(P[9], k1, P[8]*k0)) + P[11];
    float sg = __fadd_rn(__fadd_rn(__fmul_rn(g0, g0), __fmul_rn(g1, g1)),
                         __fmul_rn(g2, g2));
    return make_float4(g0, g1, g2, sg);
}

__device__ __forceinline__ float wave_red(float v) {
    #pragma unroll
    for (int off = 32; off > 0; off >>= 1) v += __shfl_down(v, off, 64);
    return v;
}

// Fused kernel (node 2 of 2; node 1 is a memset zeroing good[]+done):
//  Phase 1 (all blocks): per-(row-tile, j-chunk) "good" flags. All per-row
//    state lives in NAMED SCALARS (no arrays -> no promote-alloca demotion,
//    the R1-R4 failure mode). j-loop is a pure fmin reduction; exact
//    first-occurrence ties via <=/< split + equality-triggered prefix scan.
//  Phase 2 (last block via done-counter): balanced BCE from good[i]==numJ,
//    weighted L1, scalar combine -> out[0].
__global__ void fused_kernel(
        const float* __restrict__ kp,
        const float* __restrict__ pred,
        const float* __restrict__ pose,
        const float* __restrict__ ow,
        const float* __restrict__ logits,
        unsigned int* __restrict__ good,
        unsigned int* __restrict__ done,
        float* __restrict__ out,
        int M, int N, int numI, int numJ, int nblocks) {
    __shared__ float4 sh[JCHUNK];
    __shared__ float red[4 * 6];
    __shared__ unsigned int is_last;

    int ic = blockIdx.x % numI;
    int jc = blockIdx.x / numI;
    int j0 = jc * JCHUNK;
    int jmax = M - j0; if (jmax > JCHUNK) jmax = JCHUNK;

    // ---- stage this chunk's gt into LDS (computed from kp+pose) ----
    for (int k = threadIdx.x; k < jmax; k += TPB) {
        int j = j0 + k;
        sh[k] = compute_gt(kp + 3*j, pose + (j / N) * 12);
    }
    __syncthreads();

    // ---- per-row state: 40 named scalars, pure SSA ----
    int ibase = ic * (TPB * IT) + threadIdx.x;
#define KDECL(k) \
    float tp0_##k, tp1_##k, tp2_##k, sp_##k, m_##k; \
    { int i = ibase + (k)*TPB; if (i >= M) i = M - 1; \
      float p0 = pred[3*i+0], p1 = pred[3*i+1], p2 = pred[3*i+2]; \
      sp_##k = __fadd_rn(__fadd_rn(__fmul_rn(p0,p0), __fmul_rn(p1,p1)), \
                         __fmul_rn(p2,p2)); \
      tp0_##k = 2.0f*p0; tp1_##k = 2.0f*p1; tp2_##k = 2.0f*p2; \
      m_##k = __uint_as_float(0x7f7fffffu); }
    KDECL(0) KDECL(1) KDECL(2) KDECL(3) KDECL(4) KDECL(5) KDECL(6) KDECL(7)
#undef KDECL

    // ---- pure fmin j-loop; 11 VALU / (2 pairs) / row ----
    int j = 0;
    for (; j + 1 < jmax; j += 2) {
        float4 ga = sh[j];
        float4 gb = sh[j + 1];
#define KSTEP(k) { \
        float va = (sp_##k + ga.w) - \
            fmaf(tp2_##k, ga.z, fmaf(tp1_##k, ga.y, tp0_##k * ga.x)); \
        float vb = (sp_##k + gb.w) - \
            fmaf(tp2_##k, gb.z, fmaf(tp1_##k, gb.y, tp0_##k * gb.x)); \
        m_##k = fminf(fminf(va, vb), m_##k); }
        KSTEP(0) KSTEP(1) KSTEP(2) KSTEP(3) KSTEP(4) KSTEP(5) KSTEP(6) KSTEP(7)
#undef KSTEP
    }
    if (j < jmax) {
        float4 ga = sh[j];
#define KTAIL(k) { \
        float va = (sp_##k + ga.w) - \
            fmaf(tp2_##k, ga.z, fmaf(tp1_##k, ga.y, tp0_##k * ga.x)); \
        m_##k = fminf(va, m_##k); }
        KTAIL(0) KTAIL(1) KTAIL(2) KTAIL(3) KTAIL(4) KTAIL(5) KTAIL(6) KTAIL(7)
#undef KTAIL
    }

    // ---- exact tie resolution + rare good-flag atomic ----
    int j1 = j0 + jmax;
#define KFIN(k) { \
    int i = ibase + (k)*TPB; \
    if (i < M) { \
      float4 gi = compute_gt(kp + 3*i, pose + (i / N) * 12); \
      float dot2 = fmaf(tp2_##k, gi.z, fmaf(tp1_##k, gi.y, tp0_##k * gi.x)); \
      float dii = fmaxf((sp_##k + gi.w) - dot2, 0.0f); \
      float vminc = fmaxf(m_##k, 0.0f); \
      bool bad; \
      if (i >= j1) { bad = (vminc <= dii); } \
      else { \
        bad = (vminc < dii); \
        if (!bad && vminc == dii && i > j0) { \
          int je = (i < j1 ? i : j1) - j0; \
          for (int jj = 0; jj < je; jj++) { \
            float4 g = sh[jj]; \
            float v = (sp_##k + g.w) - \
                fmaf(tp2_##k, g.z, fmaf(tp1_##k, g.y, tp0_##k * g.x)); \
            if (fmaxf(v, 0.0f) <= dii) { bad = true; break; } \
          } \
        } \
      } \
      if (!bad) atomicAdd(&good[i], 1u); \
    } }
    KFIN(0) KFIN(1) KFIN(2) KFIN(3) KFIN(4) KFIN(5) KFIN(6) KFIN(7)
#undef KFIN

    // ---- last-block-done: finalize + scalar combine ----
    __syncthreads();
    if (threadIdx.x == 0) {
        __threadfence();                       // release good[] updates
        unsigned int prev = atomicAdd(done, 1u);
        is_last = (prev == (unsigned int)(nblocks - 1)) ? 1u : 0u;
    }
    __syncthreads();
    if (!is_last) return;
    __threadfence();                           // acquire side

    float werr = 0.f, wsum = 0.f, b1 = 0.f, c1 = 0.f, b0 = 0.f, c0 = 0.f;
    for (int i = threadIdx.x; i < M; i += TPB) {
        unsigned int g = __hip_atomic_load(&good[i], __ATOMIC_RELAXED,
                                           __HIP_MEMORY_SCOPE_AGENT);
        float x = logits[i];
        float l1p = log1pf(expf(-fabsf(x)));   // softplus tail
        if (g == (unsigned int)numJ) {         // label 1: softplus(-x)
            b1 += fmaxf(-x, 0.f) + l1p; c1 += 1.f;
        } else {                               // label 0: softplus(x)
            b0 += fmaxf(x, 0.f) + l1p;  c0 += 1.f;
        }
        float4 gg = compute_gt(kp + 3*i, pose + (i / N) * 12);
        float p0 = pred[3*i+0], p1 = pred[3*i+1], p2 = pred[3*i+2];
        float e = (fabsf(p0 - gg.x) + fabsf(p1 - gg.y)) + fabsf(p2 - gg.z);
        float wi = ow[i];
        werr += wi * e;
        wsum += wi;
    }
    werr = wave_red(werr); wsum = wave_red(wsum);
    b1 = wave_red(b1); c1 = wave_red(c1);
    b0 = wave_red(b0); c0 = wave_red(c0);
    int wid = threadIdx.x >> 6;
    if ((threadIdx.x & 63) == 0) {
        red[wid*6+0] = werr; red[wid*6+1] = wsum;
        red[wid*6+2] = b1;   red[wid*6+3] = c1;
        red[wid*6+4] = b0;   red[wid*6+5] = c0;
    }
    __syncthreads();
    if (threadIdx.x == 0) {
        float t[6];
        #pragma unroll
        for (int q = 0; q < 6; q++)
            t[q] = red[q] + red[6+q] + red[12+q] + red[18+q];
        float mean_err = t[0] / fmaxf(t[1], 1e-6f);
        float g1v = (t[3] > 0.f) ? (t[2] / fmaxf(t[3], 1.f)) : 0.f;
        float g0v = (t[5] > 0.f) ? (t[4] / fmaxf(t[5], 1.f)) : 0.f;
        out[0] = mean_err + (g0v * 0.5f + g1v * 0.5f);
    }
}

extern "C" void kernel_launch(void* const* d_in, const int* in_sizes, int n_in,
                              void* d_out, int out_size, void* d_ws, size_t ws_size,
                              hipStream_t stream) {
    const float* kp     = (const float*)d_in[0];
    const float* pred   = (const float*)d_in[1];
    const float* pose   = (const float*)d_in[2];
    const float* ow     = (const float*)d_in[3];
    const float* logits = (const float*)d_in[4];
    float* out = (float*)d_out;

    int M = in_sizes[3];            // B*N = 16384
    int B = in_sizes[2] / 12;       // 2
    int N = M / B;                  // 8192

    unsigned int* good = (unsigned int*)d_ws;                        // M u32
    unsigned int* done = (unsigned int*)((char*)d_ws + (size_t)M*4); // 1 u32

    hipMemsetAsync(d_ws, 0, (size_t)M * 4 + 16, stream);

    int numI = (M + TPB * IT - 1) / (TPB * IT);                  // 8
    int numJ = (M + JCHUNK - 1) / JCHUNK;                        // 128
    int nblocks = numI * numJ;                                   // 1024 (4/CU)
    hipLaunchKernelGGL(fused_kernel, dim3(nblocks), dim3(TPB), 0, stream,
                       kp, pred, pose, ow, logits, good, done, out,
                       M, N, numI, numJ, nblocks);
}